// Round 6
// baseline (285.696 us; speedup 1.0000x reference)
//
#include <hip/hip_runtime.h>
#include <hip/hip_bf16.h>

typedef __attribute__((ext_vector_type(8))) short short8;
typedef __attribute__((ext_vector_type(4))) float f32x4;
typedef __attribute__((ext_vector_type(2))) float f32x2;
typedef __attribute__((ext_vector_type(4))) unsigned uint4v;
typedef __attribute__((ext_vector_type(2))) unsigned uint2v;

#define NCELL 8192
#define NGENE 10000
#define KD 32
#define ZD 100
#define HD 256
#define GD 100    // z_dim of output (gen_Z rows)
#define NGBLK 313 // gene blocks of 32 (last one half-valid: genes 9984..9999)
#define NGPAD 10016

__device__ __forceinline__ float gelu_exact(float x) {
    return 0.5f * x * (1.0f + erff(x * 0.70710678118654752f));
}
__device__ __forceinline__ ushort bf16bits(float x) {
    __hip_bfloat16 h = __float2bfloat16(x);
    return *reinterpret_cast<ushort*>(&h);
}
__device__ __forceinline__ f32x4 ntload4(const float* p) {
    return __builtin_nontemporal_load(reinterpret_cast<const f32x4*>(p));
}

// ---------------- Kernel 1: keys -> bf16 hi/lo A-fragments for S^T (slot-permuted, validated)
__global__ void key_kernel(const float* __restrict__ rawZ,
                           const float* __restrict__ Wz1, const float* __restrict__ bz1,
                           const float* __restrict__ Wz2, const float* __restrict__ bz2,
                           ushort* __restrict__ khiA, ushort* __restrict__ kloA,
                           unsigned* __restrict__ kmax2u) {
    __shared__ float z[8][ZD];
    __shared__ float h[8][HD];
    const int t = threadIdx.x;
    const int c0 = blockIdx.x * 8;
    for (int idx = t; idx < 8 * ZD; idx += 256) {
        int cell = idx / ZD, i = idx - cell * ZD;
        z[cell][i] = rawZ[i * NCELL + c0 + cell];
    }
    __syncthreads();
    float a[8];
#pragma unroll
    for (int cl = 0; cl < 8; ++cl) a[cl] = bz1[t];
    for (int i = 0; i < ZD; ++i) {
        float wv = Wz1[i * HD + t];
#pragma unroll
        for (int cl = 0; cl < 8; ++cl) a[cl] += z[cl][i] * wv;
    }
#pragma unroll
    for (int cl = 0; cl < 8; ++cl) h[cl][t] = gelu_exact(a[cl]);
    __syncthreads();
    const int cell = t >> 5, kk = t & 31;
    float b = bz2[kk];
    for (int j = 0; j < HD; ++j) b += h[cell][j] * Wz2[j * KD + kk];
    const int c = c0 + cell;
    const int c16 = c & 15;
    // slot perm: makes cvt_pk+permlane output have k == linear cell (HW-validated R5)
    const int s = (c16 & 1) | (((c16 >> 2) & 1) << 1) | (((c16 >> 3) & 1) << 2) | (((c16 >> 1) & 1) << 3);
    __hip_bfloat16 hi = __float2bfloat16(b);
    float hif = __bfloat162float(hi);
    int idx = ((c >> 4) * 64 + s + 16 * (kk >> 3)) * 8 + (kk & 7);
    khiA[idx] = *reinterpret_cast<ushort*>(&hi);
    kloA[idx] = bf16bits(b - hif);
    float sq = b * b;
#pragma unroll
    for (int off = 16; off > 0; off >>= 1) sq += __shfl_xor(sq, off, 32);
    if (kk == 0) atomicMax(kmax2u, __float_as_uint(sq));
}

// ---------------- Kernel 2: q -> bf16 hi/lo B-fragments (padded to 10016 genes), Mg bound
__global__ void query_kernel(const float* __restrict__ Grep,
                             const float* __restrict__ Wg1, const float* __restrict__ bg1,
                             const float* __restrict__ Wg2, const float* __restrict__ bg2,
                             const unsigned* __restrict__ kmax2u,
                             ushort* __restrict__ qBhi, ushort* __restrict__ qBlo,
                             float* __restrict__ Mg) {
    __shared__ float gr[8][GD];
    __shared__ float hq[8][KD];
    const int t = threadIdx.x;
    const int g0 = blockIdx.x * 8;
    for (int idx = t; idx < 8 * GD; idx += 256) {
        int ge = idx / GD, i = idx - ge * GD;
        int g = g0 + ge;
        gr[ge][i] = (g < NGENE) ? Grep[(size_t)g * GD + i] : 0.0f;
    }
    __syncthreads();
    const int ge = t >> 5, kk = t & 31;
    float a = bg1[kk];
    for (int i = 0; i < GD; ++i) a += gr[ge][i] * Wg1[i * KD + kk];
    hq[ge][kk] = gelu_exact(a);
    __syncthreads();
    float b = bg2[kk];
#pragma unroll
    for (int j = 0; j < KD; ++j) b += hq[ge][j] * Wg2[j * KD + kk];
    float qv = b * 0.17677669529663687f; // fold 1/sqrt(d_k)
    const int g = g0 + ge;
    __hip_bfloat16 hi = __float2bfloat16(qv);
    float hif = __bfloat162float(hi);
    int idx = ((g >> 4) * 64 + (g & 15) + 16 * (kk >> 3)) * 8 + (kk & 7);
    qBhi[idx] = *reinterpret_cast<ushort*>(&hi);
    qBlo[idx] = bf16bits(qv - hif);
    float sq = qv * qv;
#pragma unroll
    for (int off = 16; off > 0; off >>= 1) sq += __shfl_xor(sq, off, 32);
    if (kk == 0) {
        float km2 = __uint_as_float(*kmax2u);
        Mg[g] = sqrtf(sq * km2) + 25.0f;   // static softmax shift; exp(l-M) <= 1 always
    }
}

// ---------------- Kernel 3: genZB — gen_Z bf16, PV B-fragment order, k = linear cell (validated)
__global__ void vprep_kernel(const float* __restrict__ genZ, ushort* __restrict__ genZB) {
    int o = blockIdx.x * 256 + threadIdx.x; // 1,048,576 total
    int j = o & 7;
    int l = (o >> 3) & 63;
    int db = (o >> 9) & 7;
    int cb = o >> 12;
    int c = cb * 32 + ((l >> 4) & 3) * 8 + j;
    int d = db * 16 + (l & 15);
    float v = (d < GD) ? genZ[d * NCELL + c] : 0.0f;
    genZB[o] = bf16bits(v);
}

// ---------------- Kernel 4: barrier-free fused partial, 32 genes/wave, L2-pinned streams.
// Wave = 32 genes x cells_pw cells. Block = 4 waves, same cell-slice q (L1 k/V reuse).
// Blocks mapped so each XCD hosts 1-2 q-slices (L2 working set ~1.8MB). Gumbel NT-loaded
// through a conflict-free slot-XOR LDS transpose tile. Part/Lpart NT-stored.
__launch_bounds__(256, 3)
__global__ void fused_kernel(const float* __restrict__ gumbel,
                             const ushort* __restrict__ khiA, const ushort* __restrict__ kloA,
                             const ushort* __restrict__ qBhi, const ushort* __restrict__ qBlo,
                             const float* __restrict__ Mg,
                             const ushort* __restrict__ genZB,
                             float* __restrict__ part, float* __restrict__ Lpart,
                             int Q, int cells_pw) {
    __shared__ __align__(16) float glds[4][2][1024];   // 32 KB: 4 waves x dbuf x [32g][32c]
    const int t = threadIdx.x, lane = t & 63, w = t >> 6;
    const int b = blockIdx.x;
    int q, ib;
    if (Q >= 8) { q = (b & 7) + 8 * ((b >> 3) / 79); ib = (b >> 3) % 79; }
    else        { q = b % Q;                         ib = b / Q; }
    const int gblk = ib * 4 + w;
    if (gblk >= NGBLK) return;
    const int g0 = gblk * 32;
    const int cbase = q * cells_pw;
    const int nsteps = cells_pw >> 5;
    const int wv = q * NGBLK + gblk;

    // ---- q fragments (2 groups of 16 genes), static-max shifts
    const int gx = lane & 15;
    short8 qh0 = *reinterpret_cast<const short8*>(qBhi + (size_t)(gblk * 2) * 512 + lane * 8);
    short8 ql0 = *reinterpret_cast<const short8*>(qBlo + (size_t)(gblk * 2) * 512 + lane * 8);
    short8 qh1 = *reinterpret_cast<const short8*>(qBhi + (size_t)(gblk * 2 + 1) * 512 + lane * 8);
    short8 ql1 = *reinterpret_cast<const short8*>(qBlo + (size_t)(gblk * 2 + 1) * 512 + lane * 8);
    const float negM0 = -Mg[g0 + gx];
    const float negM1 = -Mg[g0 + 16 + gx];

    // ---- gumbel staging addresses. Write: lane -> row=lane>>1, cols 16*(lane&1)+4j..+3.
    // LDS slot-XOR swizzle (16B slots): float idx = row*32 + ((slot ^ (row&7))<<2) + (c&3).
    // Conflict-free for both the 4x f32x4 writes and the 8x f32x2 reads (bank-counted).
    const int grow = g0 + (lane >> 1);
    const float* gptr = gumbel + (size_t)(grow < NGENE ? grow : NGENE - 1) * NCELL
                        + cbase + 16 * (lane & 1);
    float* wlds = &glds[w][0][0];
    const int r7 = (lane >> 1) & 7;
    int wr[4];
#pragma unroll
    for (int j = 0; j < 4; ++j) wr[j] = (lane >> 1) * 32 + ((4 * (lane & 1) + j) ^ r7) * 4;
    const int e7 = gx & 7, bb = lane >> 4;
    const int clo = 2 * (bb >> 1) + 8 * (bb & 1);  // inverse slot perm (validated R5)
#define SWZ(c) ((((c) >> 2) ^ e7) * 4 + ((c) & 3))
    const int rd0 = gx * 32 + SWZ(clo);
    const int rd1 = gx * 32 + SWZ(clo + 4);
    const int rd2 = gx * 32 + SWZ(clo + 16);
    const int rd3 = gx * 32 + SWZ(clo + 20);
#undef SWZ

    // prologue: stage step-0 gumbel into buf0
#pragma unroll
    for (int j = 0; j < 4; ++j)
        *reinterpret_cast<f32x4*>(wlds + wr[j]) = ntload4(gptr + 4 * j);

    f32x4 acc[14];
#pragma unroll
    for (int i = 0; i < 14; ++i) acc[i] = f32x4{0.f, 0.f, 0.f, 0.f};
    float L0 = 0.f, L1 = 0.f;
    const ushort* kp  = khiA + (size_t)(cbase >> 4) * 512 + lane * 8;
    const ushort* klp = kloA + (size_t)(cbase >> 4) * 512 + lane * 8;
    const short8* vb  = reinterpret_cast<const short8*>(genZB) + (size_t)(cbase >> 5) * 512 + lane;
    const f32x4 z4 = {0.f, 0.f, 0.f, 0.f};
    int cur = 0;

    for (int s = 0; s < nsteps; ++s) {
        // k fragments for the 2 c-tiles of this 32-cell step (L2-resident)
        short8 kh0 = *reinterpret_cast<const short8*>(kp);
        short8 kh1 = *reinterpret_cast<const short8*>(kp + 512);
        short8 kl0 = *reinterpret_cast<const short8*>(klp);
        short8 kl1 = *reinterpret_cast<const short8*>(klp + 512);
        kp += 1024; klp += 1024;
        // next-step gumbel prefetch (nontemporal, coalesced)
        const int snext = (s + 1 < nsteps) ? s + 1 : s;
        f32x4 gn0 = ntload4(gptr + (size_t)snext * 32);
        f32x4 gn1 = ntload4(gptr + (size_t)snext * 32 + 4);
        f32x4 gn2 = ntload4(gptr + (size_t)snext * 32 + 8);
        f32x4 gn3 = ntload4(gptr + (size_t)snext * 32 + 12);
        // current gumbel from LDS (both gene groups)
        const float* rb = wlds + cur * 1024;
        f32x2 u0 = *reinterpret_cast<const f32x2*>(rb + rd0);
        f32x2 u1 = *reinterpret_cast<const f32x2*>(rb + rd1);
        f32x2 u2 = *reinterpret_cast<const f32x2*>(rb + rd2);
        f32x2 u3 = *reinterpret_cast<const f32x2*>(rb + rd3);
        f32x2 u4 = *reinterpret_cast<const f32x2*>(rb + 512 + rd0);
        f32x2 u5 = *reinterpret_cast<const f32x2*>(rb + 512 + rd1);
        f32x2 u6 = *reinterpret_cast<const f32x2*>(rb + 512 + rd2);
        f32x2 u7 = *reinterpret_cast<const f32x2*>(rb + 512 + rd3);
        // S^T = K x Q, 3-term bf16 split, both gene groups share k-frags
        f32x4 s00 = __builtin_amdgcn_mfma_f32_16x16x32_bf16(kh0, qh0, z4, 0, 0, 0);
        s00 = __builtin_amdgcn_mfma_f32_16x16x32_bf16(kl0, qh0, s00, 0, 0, 0);
        s00 = __builtin_amdgcn_mfma_f32_16x16x32_bf16(kh0, ql0, s00, 0, 0, 0);
        f32x4 s01 = __builtin_amdgcn_mfma_f32_16x16x32_bf16(kh1, qh0, z4, 0, 0, 0);
        s01 = __builtin_amdgcn_mfma_f32_16x16x32_bf16(kl1, qh0, s01, 0, 0, 0);
        s01 = __builtin_amdgcn_mfma_f32_16x16x32_bf16(kh1, ql0, s01, 0, 0, 0);
        f32x4 s10 = __builtin_amdgcn_mfma_f32_16x16x32_bf16(kh0, qh1, z4, 0, 0, 0);
        s10 = __builtin_amdgcn_mfma_f32_16x16x32_bf16(kl0, qh1, s10, 0, 0, 0);
        s10 = __builtin_amdgcn_mfma_f32_16x16x32_bf16(kh0, ql1, s10, 0, 0, 0);
        f32x4 s11 = __builtin_amdgcn_mfma_f32_16x16x32_bf16(kh1, qh1, z4, 0, 0, 0);
        s11 = __builtin_amdgcn_mfma_f32_16x16x32_bf16(kl1, qh1, s11, 0, 0, 0);
        s11 = __builtin_amdgcn_mfma_f32_16x16x32_bf16(kh1, ql1, s11, 0, 0, 0);
        // exp(S + gumbel - M) and pack to PV A-frags (validated cvt_pk+permlane path)
        float p0 = __expf(s00.x + u0.x + negM0);
        float p1 = __expf(s00.y + u0.y + negM0);
        float p2 = __expf(s00.z + u1.x + negM0);
        float p3 = __expf(s00.w + u1.y + negM0);
        float p4 = __expf(s01.x + u2.x + negM0);
        float p5 = __expf(s01.y + u2.y + negM0);
        float p6 = __expf(s01.z + u3.x + negM0);
        float p7 = __expf(s01.w + u3.y + negM0);
        L0 += ((p0 + p1) + (p2 + p3)) + ((p4 + p5) + (p6 + p7));
        unsigned w00, w01, w10, w11;
        asm("v_cvt_pk_bf16_f32 %0, %1, %2" : "=v"(w00) : "v"(p0), "v"(p1));
        asm("v_cvt_pk_bf16_f32 %0, %1, %2" : "=v"(w01) : "v"(p2), "v"(p3));
        asm("v_cvt_pk_bf16_f32 %0, %1, %2" : "=v"(w10) : "v"(p4), "v"(p5));
        asm("v_cvt_pk_bf16_f32 %0, %1, %2" : "=v"(w11) : "v"(p6), "v"(p7));
        uint2v rA = __builtin_amdgcn_permlane32_swap(w00, w10, false, false);
        uint2v rB = __builtin_amdgcn_permlane32_swap(w01, w11, false, false);
        uint4v pau0 = {rA.x, rA.y, rB.x, rB.y};
        short8 pa0 = *reinterpret_cast<short8*>(&pau0);
        float r0 = __expf(s10.x + u4.x + negM1);
        float r1 = __expf(s10.y + u4.y + negM1);
        float r2 = __expf(s10.z + u5.x + negM1);
        float r3 = __expf(s10.w + u5.y + negM1);
        float r4 = __expf(s11.x + u6.x + negM1);
        float r5 = __expf(s11.y + u6.y + negM1);
        float r6 = __expf(s11.z + u7.x + negM1);
        float r7v = __expf(s11.w + u7.y + negM1);
        L1 += ((r0 + r1) + (r2 + r3)) + ((r4 + r5) + (r6 + r7v));
        unsigned x00, x01, x10, x11;
        asm("v_cvt_pk_bf16_f32 %0, %1, %2" : "=v"(x00) : "v"(r0), "v"(r1));
        asm("v_cvt_pk_bf16_f32 %0, %1, %2" : "=v"(x01) : "v"(r2), "v"(r3));
        asm("v_cvt_pk_bf16_f32 %0, %1, %2" : "=v"(x10) : "v"(r4), "v"(r5));
        asm("v_cvt_pk_bf16_f32 %0, %1, %2" : "=v"(x11) : "v"(r6), "v"(r7v));
        uint2v rC = __builtin_amdgcn_permlane32_swap(x00, x10, false, false);
        uint2v rD = __builtin_amdgcn_permlane32_swap(x01, x11, false, false);
        uint4v pau1 = {rC.x, rC.y, rD.x, rD.y};
        short8 pa1 = *reinterpret_cast<short8*>(&pau1);
        // PV: 7 d-tiles x 2 groups, V-frags shared; split loads to bound registers
        {
            short8 v0 = vb[0], v1 = vb[64], v2 = vb[128], v3 = vb[192];
            acc[0]  = __builtin_amdgcn_mfma_f32_16x16x32_bf16(pa0, v0, acc[0],  0, 0, 0);
            acc[7]  = __builtin_amdgcn_mfma_f32_16x16x32_bf16(pa1, v0, acc[7],  0, 0, 0);
            acc[1]  = __builtin_amdgcn_mfma_f32_16x16x32_bf16(pa0, v1, acc[1],  0, 0, 0);
            acc[8]  = __builtin_amdgcn_mfma_f32_16x16x32_bf16(pa1, v1, acc[8],  0, 0, 0);
            acc[2]  = __builtin_amdgcn_mfma_f32_16x16x32_bf16(pa0, v2, acc[2],  0, 0, 0);
            acc[9]  = __builtin_amdgcn_mfma_f32_16x16x32_bf16(pa1, v2, acc[9],  0, 0, 0);
            acc[3]  = __builtin_amdgcn_mfma_f32_16x16x32_bf16(pa0, v3, acc[3],  0, 0, 0);
            acc[10] = __builtin_amdgcn_mfma_f32_16x16x32_bf16(pa1, v3, acc[10], 0, 0, 0);
        }
        {
            short8 v4 = vb[256], v5 = vb[320], v6 = vb[384];
            acc[4]  = __builtin_amdgcn_mfma_f32_16x16x32_bf16(pa0, v4, acc[4],  0, 0, 0);
            acc[11] = __builtin_amdgcn_mfma_f32_16x16x32_bf16(pa1, v4, acc[11], 0, 0, 0);
            acc[5]  = __builtin_amdgcn_mfma_f32_16x16x32_bf16(pa0, v5, acc[5],  0, 0, 0);
            acc[12] = __builtin_amdgcn_mfma_f32_16x16x32_bf16(pa1, v5, acc[12], 0, 0, 0);
            acc[6]  = __builtin_amdgcn_mfma_f32_16x16x32_bf16(pa0, v6, acc[6],  0, 0, 0);
            acc[13] = __builtin_amdgcn_mfma_f32_16x16x32_bf16(pa1, v6, acc[13], 0, 0, 0);
        }
        vb += 512;
        // stage next gumbel (wave-private buffer; lgkmcnt-ordered, no barrier)
        float* wb = wlds + (cur ^ 1) * 1024;
        *reinterpret_cast<f32x4*>(wb + wr[0]) = gn0;
        *reinterpret_cast<f32x4*>(wb + wr[1]) = gn1;
        *reinterpret_cast<f32x4*>(wb + wr[2]) = gn2;
        *reinterpret_cast<f32x4*>(wb + wr[3]) = gn3;
        cur ^= 1;
    }
    // L: lanes sharing gx hold disjoint-cell partials of the same gene
    L0 += __shfl_xor(L0, 16, 64);
    L0 += __shfl_xor(L0, 32, 64);
    L1 += __shfl_xor(L1, 16, 64);
    L1 += __shfl_xor(L1, 32, 64);
    if (lane < 16) {
        __builtin_nontemporal_store(L0, Lpart + (size_t)wv * 32 + lane);
        __builtin_nontemporal_store(L1, Lpart + (size_t)wv * 32 + 16 + lane);
    }
    float* pp = part + (size_t)wv * 14 * 256;
#pragma unroll
    for (int tile = 0; tile < 14; ++tile)
        __builtin_nontemporal_store(acc[tile],
            reinterpret_cast<f32x4*>(pp + tile * 256 + lane * 4));
}

// ---------------- Kernel 5: combine partials + normalize
__global__ void combine_kernel(const float* __restrict__ part, const float* __restrict__ Lpart,
                               int Q, float* __restrict__ out) {
    const int gblk = blockIdx.x;  // 313
    const int t = threadIdx.x;    // 256
    __shared__ float Linv[32];
    if (t < 32) {
        float s = 0.f;
        for (int qq = 0; qq < Q; ++qq) s += Lpart[(size_t)(qq * NGBLK + gblk) * 32 + t];
        Linv[t] = 1.0f / s;
    }
    __syncthreads();
    for (int pos = t; pos < 14 * 64; pos += 256) {
        const int tile = pos >> 6, lane = pos & 63;
        const int grp = tile / 7, db = tile % 7;
        const int d = db * 16 + (lane & 15);
        f32x4 ssum = {0.f, 0.f, 0.f, 0.f};
        for (int qq = 0; qq < Q; ++qq)
            ssum += *reinterpret_cast<const f32x4*>(
                part + ((size_t)(qq * NGBLK + gblk) * 14 + tile) * 256 + lane * 4);
        const int gl0 = grp * 16 + 4 * (lane >> 4);
        const int gene0 = gblk * 32 + gl0;
        if (d < GD && gene0 < NGENE) {
            f32x4 li = {Linv[gl0], Linv[gl0 + 1], Linv[gl0 + 2], Linv[gl0 + 3]};
            f32x4 o = ssum * li;
            *reinterpret_cast<f32x4*>(out + (size_t)d * NGENE + gene0) = o;
        }
    }
}

extern "C" void kernel_launch(void* const* d_in, const int* in_sizes, int n_in,
                              void* d_out, int out_size, void* d_ws, size_t ws_size,
                              hipStream_t stream) {
    const float* rawZ  = (const float*)d_in[0];
    const float* genZ  = (const float*)d_in[1];
    const float* Grep  = (const float*)d_in[2];
    const float* gumb  = (const float*)d_in[3];
    const float* Wz1   = (const float*)d_in[4];
    const float* bz1   = (const float*)d_in[5];
    const float* Wz2   = (const float*)d_in[6];
    const float* bz2   = (const float*)d_in[7];
    const float* Wg1   = (const float*)d_in[8];
    const float* bg1   = (const float*)d_in[9];
    const float* Wg2   = (const float*)d_in[10];
    const float* bg2   = (const float*)d_in[11];
    float* out = (float*)d_out;

    char* ws = (char*)d_ws;
    ushort*   khiA  = (ushort*)ws;                           // 512K
    ushort*   kloA  = (ushort*)(ws + 524288);                // 512K
    ushort*   qBhi  = (ushort*)(ws + 1048576);               // 640K (10016 genes)
    ushort*   qBlo  = (ushort*)(ws + 1703936);               // 640K
    ushort*   genZB = (ushort*)(ws + 2359296);               // 2M
    float*    MgA   = (float*)(ws + 4456448);                // 40K
    unsigned* kmax  = (unsigned*)(ws + 4497408);             // 256B
    const size_t base_off = 4497664;

    // cell-split factor: waves = 313*Q; fall back if workspace too small
    const size_t per_q = (size_t)NGBLK * (14 * 256 + 32) * 4;  // part + Lpart per q-slice
    int Q = 16;
    while (Q > 1 && base_off + (size_t)Q * per_q > ws_size) Q >>= 1;
    float* partA  = (float*)(ws + base_off);
    float* LpartA = partA + (size_t)Q * NGBLK * 14 * 256;

    hipMemsetAsync(kmax, 0, 4, stream);
    hipLaunchKernelGGL(key_kernel,   dim3(NCELL / 8), dim3(256), 0, stream,
                       rawZ, Wz1, bz1, Wz2, bz2, khiA, kloA, kmax);
    hipLaunchKernelGGL(query_kernel, dim3(NGPAD / 8), dim3(256), 0, stream,
                       Grep, Wg1, bg1, Wg2, bg2, kmax, qBhi, qBlo, MgA);
    hipLaunchKernelGGL(vprep_kernel, dim3((256 * 8 * 64 * 8) / 256), dim3(256), 0, stream,
                       genZ, genZB);
    hipLaunchKernelGGL(fused_kernel, dim3(Q * 79), dim3(256), 0, stream,
                       gumb, khiA, kloA, qBhi, qBlo, MgA, genZB, partA, LpartA,
                       Q, NCELL / Q);
    hipLaunchKernelGGL(combine_kernel, dim3(NGBLK), dim3(256), 0, stream,
                       partA, LpartA, Q, out);
}

// Round 7
// 256.105 us; speedup vs baseline: 1.1155x; 1.1155x over previous
//
#include <hip/hip_runtime.h>
#include <hip/hip_bf16.h>

typedef __attribute__((ext_vector_type(8))) short short8;
typedef __attribute__((ext_vector_type(4))) float f32x4;
typedef __attribute__((ext_vector_type(4))) unsigned uint4v;
typedef __attribute__((ext_vector_type(2))) unsigned uint2v;

#define NCELL 8192
#define NGENE 10000
#define KD 32
#define ZD 100
#define HD 256
#define GD 100    // z_dim of output (gen_Z rows)
#define NGB 625   // gene blocks of 16 (625*16 == 10000 exactly)
#define NGPAD 10016

__device__ __forceinline__ float gelu_exact(float x) {
    return 0.5f * x * (1.0f + erff(x * 0.70710678118654752f));
}
__device__ __forceinline__ ushort bf16bits(float x) {
    __hip_bfloat16 h = __float2bfloat16(x);
    return *reinterpret_cast<ushort*>(&h);
}
__device__ __forceinline__ f32x4 ntload4(const float* p) {
    return __builtin_nontemporal_load(reinterpret_cast<const f32x4*>(p));
}

// ---------------- Kernel 1: keys -> bf16 hi/lo A-fragments for S^T.
// NEW slot perm: cell group G=c16>>2 -> slot group cmap(G) (cmap = 2-bit reverse: 0,2,1,3).
// Chosen so per-lane gumbel adds are contiguous f32x4 AND cvt_pk+permlane lands in tau-order.
__global__ void key_kernel(const float* __restrict__ rawZ,
                           const float* __restrict__ Wz1, const float* __restrict__ bz1,
                           const float* __restrict__ Wz2, const float* __restrict__ bz2,
                           ushort* __restrict__ khiA, ushort* __restrict__ kloA,
                           unsigned* __restrict__ kmax2u) {
    __shared__ float z[8][ZD];
    __shared__ float h[8][HD];
    const int t = threadIdx.x;
    const int c0 = blockIdx.x * 8;
    for (int idx = t; idx < 8 * ZD; idx += 256) {
        int cell = idx / ZD, i = idx - cell * ZD;
        z[cell][i] = rawZ[i * NCELL + c0 + cell];
    }
    __syncthreads();
    float a[8];
#pragma unroll
    for (int cl = 0; cl < 8; ++cl) a[cl] = bz1[t];
    for (int i = 0; i < ZD; ++i) {
        float wv = Wz1[i * HD + t];
#pragma unroll
        for (int cl = 0; cl < 8; ++cl) a[cl] += z[cl][i] * wv;
    }
#pragma unroll
    for (int cl = 0; cl < 8; ++cl) h[cl][t] = gelu_exact(a[cl]);
    __syncthreads();
    const int cell = t >> 5, kk = t & 31;
    float b = bz2[kk];
    for (int j = 0; j < HD; ++j) b += h[cell][j] * Wz2[j * KD + kk];
    const int c = c0 + cell;
    const int c16 = c & 15;
    const int G = c16 >> 2;
    const int s = (c16 & 3) | ((((G & 1) << 1) | (G >> 1)) << 2);  // slot = (c&3) | cmap(G)<<2
    __hip_bfloat16 hi = __float2bfloat16(b);
    float hif = __bfloat162float(hi);
    int idx = ((c >> 4) * 64 + s + 16 * (kk >> 3)) * 8 + (kk & 7);
    khiA[idx] = *reinterpret_cast<ushort*>(&hi);
    kloA[idx] = bf16bits(b - hif);
    float sq = b * b;
#pragma unroll
    for (int off = 16; off > 0; off >>= 1) sq += __shfl_xor(sq, off, 32);
    if (kk == 0) atomicMax(kmax2u, __float_as_uint(sq));
}

// ---------------- Kernel 2: q -> bf16 hi/lo B-fragments (padded to 10016 genes), Mg bound
__global__ void query_kernel(const float* __restrict__ Grep,
                             const float* __restrict__ Wg1, const float* __restrict__ bg1,
                             const float* __restrict__ Wg2, const float* __restrict__ bg2,
                             const unsigned* __restrict__ kmax2u,
                             ushort* __restrict__ qBhi, ushort* __restrict__ qBlo,
                             float* __restrict__ Mg) {
    __shared__ float gr[8][GD];
    __shared__ float hq[8][KD];
    const int t = threadIdx.x;
    const int g0 = blockIdx.x * 8;
    for (int idx = t; idx < 8 * GD; idx += 256) {
        int ge = idx / GD, i = idx - ge * GD;
        int g = g0 + ge;
        gr[ge][i] = (g < NGENE) ? Grep[(size_t)g * GD + i] : 0.0f;
    }
    __syncthreads();
    const int ge = t >> 5, kk = t & 31;
    float a = bg1[kk];
    for (int i = 0; i < GD; ++i) a += gr[ge][i] * Wg1[i * KD + kk];
    hq[ge][kk] = gelu_exact(a);
    __syncthreads();
    float b = bg2[kk];
#pragma unroll
    for (int j = 0; j < KD; ++j) b += hq[ge][j] * Wg2[j * KD + kk];
    float qv = b * 0.17677669529663687f; // fold 1/sqrt(d_k)
    const int g = g0 + ge;
    __hip_bfloat16 hi = __float2bfloat16(qv);
    float hif = __bfloat162float(hi);
    int idx = ((g >> 4) * 64 + (g & 15) + 16 * (kk >> 3)) * 8 + (kk & 7);
    qBhi[idx] = *reinterpret_cast<ushort*>(&hi);
    qBlo[idx] = bf16bits(qv - hif);
    float sq = qv * qv;
#pragma unroll
    for (int off = 16; off > 0; off >>= 1) sq += __shfl_xor(sq, off, 32);
    if (kk == 0) {
        float km2 = __uint_as_float(*kmax2u);
        Mg[g] = sqrtf(sq * km2) + 25.0f;   // static softmax shift; exp(l-M) <= 1 always
    }
}

// ---------------- Kernel 3: genZB — gen_Z bf16, PV B-frag order, k-cell order = tau
// tau(j) = [0,1,4,5,2,3,6,7]: bit0=j0, bit1=j2, bit2=j1 (matches post-permlane P order)
__global__ void vprep_kernel(const float* __restrict__ genZ, ushort* __restrict__ genZB) {
    int o = blockIdx.x * 256 + threadIdx.x; // 1,048,576 total
    int j = o & 7;
    int tj = (j & 1) | ((j & 2) << 1) | ((j & 4) >> 1);
    int l = (o >> 3) & 63;
    int db = (o >> 9) & 7;
    int cb = o >> 12;
    int c = cb * 32 + ((l >> 4) & 3) * 8 + tj;
    int d = db * 16 + (l & 15);
    float v = (d < GD) ? genZ[d * NCELL + c] : 0.0f;
    genZB[o] = bf16bits(v);
}

// ---------------- Kernel 4: fused partial — ZERO LDS, zero barriers, pure streaming.
// Wave = 16 genes x cells_pw cells, fully independent. Per 32-cell step:
// 4 k-loads + 2 gumbel f32x4 (contiguous, NT) + 7 V-loads -> 6 S-MFMA -> 8 exp ->
// cvt_pk+permlane32 -> 7 PV-MFMA. Blocks mapped q=b%8 so each XCD's K/V slice pins in L2.
__launch_bounds__(256, 4)
__global__ void fused_kernel(const float* __restrict__ gumbel,
                             const ushort* __restrict__ khiA, const ushort* __restrict__ kloA,
                             const ushort* __restrict__ qBhi, const ushort* __restrict__ qBlo,
                             const float* __restrict__ Mg,
                             const ushort* __restrict__ genZB,
                             float* __restrict__ part, float* __restrict__ Lpart,
                             int Q, int cells_pw) {
    const int t = threadIdx.x, lane = t & 63, w = t >> 6;
    const int b = blockIdx.x;
    const int q = b % Q;            // Q==8: q == XCD id under round-robin dispatch
    const int ib = b / Q;
    const int gblk = ib * 4 + w;
    if (gblk >= NGB) return;
    const int g0 = gblk * 16;
    const int cbase = q * cells_pw;
    const int nsteps = cells_pw >> 5;
    const int wv = q * NGB + gblk;

    const int gx = lane & 15, bq = lane >> 4;
    const int cmap4 = (((bq & 1) << 1) | (bq >> 1)) << 2;   // cmap(b)*4 in {0,8,4,12}
    const float negM = -Mg[g0 + gx];
    short8 qh = *reinterpret_cast<const short8*>(qBhi + (size_t)gblk * 512 + lane * 8);
    short8 ql = *reinterpret_cast<const short8*>(qBlo + (size_t)gblk * 512 + lane * 8);

    // gumbel: lane reads row g0+gx, cols cbase + step*32 + {cmap4..cmap4+3, +16}
    const float* gptr = gumbel + (size_t)(g0 + gx) * NCELL + cbase + cmap4;
    const ushort* kp  = khiA + (size_t)(cbase >> 4) * 512 + lane * 8;
    const ushort* klp = kloA + (size_t)(cbase >> 4) * 512 + lane * 8;
    const short8* vb  = reinterpret_cast<const short8*>(genZB) + (size_t)(cbase >> 5) * 512 + lane;

    f32x4 acc[7];
#pragma unroll
    for (int i = 0; i < 7; ++i) acc[i] = f32x4{0.f, 0.f, 0.f, 0.f};
    float L = 0.f;
    const f32x4 z4 = {0.f, 0.f, 0.f, 0.f};

    for (int s = 0; s < nsteps; ++s) {
        short8 kh0 = *reinterpret_cast<const short8*>(kp);
        short8 kh1 = *reinterpret_cast<const short8*>(kp + 512);
        short8 kl0 = *reinterpret_cast<const short8*>(klp);
        short8 kl1 = *reinterpret_cast<const short8*>(klp + 512);
        kp += 1024; klp += 1024;
        f32x4 u0 = ntload4(gptr);          // T0: cells cmap(b)*4 + 0..3 == slots 4b+0..3
        f32x4 u1 = ntload4(gptr + 16);     // T1
        gptr += 32;
        // S^T = K x Q (A=K slot-permuted, B=Q), 3-term bf16 split
        f32x4 s0 = __builtin_amdgcn_mfma_f32_16x16x32_bf16(kh0, qh, z4, 0, 0, 0);
        s0 = __builtin_amdgcn_mfma_f32_16x16x32_bf16(kl0, qh, s0, 0, 0, 0);
        s0 = __builtin_amdgcn_mfma_f32_16x16x32_bf16(kh0, ql, s0, 0, 0, 0);
        f32x4 s1 = __builtin_amdgcn_mfma_f32_16x16x32_bf16(kh1, qh, z4, 0, 0, 0);
        s1 = __builtin_amdgcn_mfma_f32_16x16x32_bf16(kl1, qh, s1, 0, 0, 0);
        s1 = __builtin_amdgcn_mfma_f32_16x16x32_bf16(kh1, ql, s1, 0, 0, 0);
        // V fragments (7 d-tiles, tau k-order)
        short8 v0 = vb[0],   v1 = vb[64],  v2 = vb[128], v3 = vb[192];
        short8 v4 = vb[256], v5 = vb[320], v6 = vb[384];
        vb += 512;
        // p = exp(S + gumbel - M); gumbel element r aligns with C/D row r by construction
        float p0 = __expf(s0.x + u0.x + negM);
        float p1 = __expf(s0.y + u0.y + negM);
        float p2 = __expf(s0.z + u0.z + negM);
        float p3 = __expf(s0.w + u0.w + negM);
        float p4 = __expf(s1.x + u1.x + negM);
        float p5 = __expf(s1.y + u1.y + negM);
        float p6 = __expf(s1.z + u1.z + negM);
        float p7 = __expf(s1.w + u1.w + negM);
        L += ((p0 + p1) + (p2 + p3)) + ((p4 + p5) + (p6 + p7));
        // pack + half-swap -> PV A-frag in tau k-order (validated mechanism R5/R6)
        unsigned w00, w01, w10, w11;
        asm("v_cvt_pk_bf16_f32 %0, %1, %2" : "=v"(w00) : "v"(p0), "v"(p1));
        asm("v_cvt_pk_bf16_f32 %0, %1, %2" : "=v"(w01) : "v"(p2), "v"(p3));
        asm("v_cvt_pk_bf16_f32 %0, %1, %2" : "=v"(w10) : "v"(p4), "v"(p5));
        asm("v_cvt_pk_bf16_f32 %0, %1, %2" : "=v"(w11) : "v"(p6), "v"(p7));
        uint2v rA = __builtin_amdgcn_permlane32_swap(w00, w10, false, false);
        uint2v rB = __builtin_amdgcn_permlane32_swap(w01, w11, false, false);
        uint4v pau = {rA.x, rA.y, rB.x, rB.y};
        short8 pa = *reinterpret_cast<short8*>(&pau);
        // PV: 7 independent MFMAs
        acc[0] = __builtin_amdgcn_mfma_f32_16x16x32_bf16(pa, v0, acc[0], 0, 0, 0);
        acc[1] = __builtin_amdgcn_mfma_f32_16x16x32_bf16(pa, v1, acc[1], 0, 0, 0);
        acc[2] = __builtin_amdgcn_mfma_f32_16x16x32_bf16(pa, v2, acc[2], 0, 0, 0);
        acc[3] = __builtin_amdgcn_mfma_f32_16x16x32_bf16(pa, v3, acc[3], 0, 0, 0);
        acc[4] = __builtin_amdgcn_mfma_f32_16x16x32_bf16(pa, v4, acc[4], 0, 0, 0);
        acc[5] = __builtin_amdgcn_mfma_f32_16x16x32_bf16(pa, v5, acc[5], 0, 0, 0);
        acc[6] = __builtin_amdgcn_mfma_f32_16x16x32_bf16(pa, v6, acc[6], 0, 0, 0);
    }
    // L: lanes sharing gx hold disjoint-cell partials of the same gene
    L += __shfl_xor(L, 16, 64);
    L += __shfl_xor(L, 32, 64);
    if (lane < 16)
        __builtin_nontemporal_store(L, Lpart + (size_t)wv * 16 + lane);
    float* pp = part + (size_t)wv * 7 * 256;
#pragma unroll
    for (int tile = 0; tile < 7; ++tile)
        __builtin_nontemporal_store(acc[tile],
            reinterpret_cast<f32x4*>(pp + tile * 256 + lane * 4));
}

// ---------------- Kernel 5: combine partials + normalize
__global__ void combine_kernel(const float* __restrict__ part, const float* __restrict__ Lpart,
                               int Q, float* __restrict__ out) {
    const int gb = blockIdx.x;   // 625
    const int t = threadIdx.x;   // 512
    __shared__ float Linv[16];
    if (t < 16) {
        float s = 0.f;
        for (int qq = 0; qq < Q; ++qq) s += Lpart[(size_t)(qq * NGB + gb) * 16 + t];
        Linv[t] = 1.0f / s;
    }
    __syncthreads();
    if (t < 448) {
        const int tile = t >> 6, lane = t & 63;
        const int d = tile * 16 + (lane & 15);
        f32x4 ssum = {0.f, 0.f, 0.f, 0.f};
        for (int qq = 0; qq < Q; ++qq)
            ssum += *reinterpret_cast<const f32x4*>(
                part + ((size_t)(qq * NGB + gb) * 7 + tile) * 256 + lane * 4);
        if (d < GD) {
            const int gl0 = 4 * (lane >> 4);   // C/D: col=lane&15 (d), row=4*(lane>>4)+r (gene)
            f32x4 li = {Linv[gl0], Linv[gl0 + 1], Linv[gl0 + 2], Linv[gl0 + 3]};
            f32x4 o = ssum * li;
            *reinterpret_cast<f32x4*>(out + (size_t)d * NGENE + gb * 16 + gl0) = o;
        }
    }
}

extern "C" void kernel_launch(void* const* d_in, const int* in_sizes, int n_in,
                              void* d_out, int out_size, void* d_ws, size_t ws_size,
                              hipStream_t stream) {
    const float* rawZ  = (const float*)d_in[0];
    const float* genZ  = (const float*)d_in[1];
    const float* Grep  = (const float*)d_in[2];
    const float* gumb  = (const float*)d_in[3];
    const float* Wz1   = (const float*)d_in[4];
    const float* bz1   = (const float*)d_in[5];
    const float* Wz2   = (const float*)d_in[6];
    const float* bz2   = (const float*)d_in[7];
    const float* Wg1   = (const float*)d_in[8];
    const float* bg1   = (const float*)d_in[9];
    const float* Wg2   = (const float*)d_in[10];
    const float* bg2   = (const float*)d_in[11];
    float* out = (float*)d_out;

    char* ws = (char*)d_ws;
    ushort*   khiA  = (ushort*)ws;                           // 512K
    ushort*   kloA  = (ushort*)(ws + 524288);                // 512K
    ushort*   qBhi  = (ushort*)(ws + 1048576);               // 640K (10016 genes)
    ushort*   qBlo  = (ushort*)(ws + 1703936);               // 640K
    ushort*   genZB = (ushort*)(ws + 2359296);               // 2M
    float*    MgA   = (float*)(ws + 4456448);                // 40K
    unsigned* kmax  = (unsigned*)(ws + 4497408);             // 256B
    const size_t base_off = 4497664;

    // cell-split factor: waves = 625*Q; fall back if workspace too small
    const size_t per_q = (size_t)NGB * (7 * 256 + 16) * 4;   // part + Lpart per q-slice
    int Q = 8;
    while (Q > 1 && base_off + (size_t)Q * per_q > ws_size) Q >>= 1;
    float* partA  = (float*)(ws + base_off);
    float* LpartA = partA + (size_t)Q * NGB * 7 * 256;

    hipMemsetAsync(kmax, 0, 4, stream);
    hipLaunchKernelGGL(key_kernel,   dim3(NCELL / 8), dim3(256), 0, stream,
                       rawZ, Wz1, bz1, Wz2, bz2, khiA, kloA, kmax);
    hipLaunchKernelGGL(query_kernel, dim3(NGPAD / 8), dim3(256), 0, stream,
                       Grep, Wg1, bg1, Wg2, bg2, kmax, qBhi, qBlo, MgA);
    hipLaunchKernelGGL(vprep_kernel, dim3((256 * 8 * 64 * 8) / 256), dim3(256), 0, stream,
                       genZ, genZB);
    hipLaunchKernelGGL(fused_kernel, dim3(Q * 157), dim3(256), 0, stream,
                       gumb, khiA, kloA, qBhi, qBlo, MgA, genZB, partA, LpartA,
                       Q, NCELL / Q);
    hipLaunchKernelGGL(combine_kernel, dim3(NGB), dim3(512), 0, stream,
                       partA, LpartA, Q, out);
}

// Round 8
// 246.816 us; speedup vs baseline: 1.1575x; 1.0376x over previous
//
#include <hip/hip_runtime.h>
#include <hip/hip_bf16.h>

typedef __attribute__((ext_vector_type(8))) short short8;
typedef __attribute__((ext_vector_type(4))) float f32x4;
typedef __attribute__((ext_vector_type(4))) unsigned uint4v;
typedef __attribute__((ext_vector_type(2))) unsigned uint2v;

#define NCELL 8192
#define NGENE 10000
#define KD 32
#define ZD 100
#define HD 256
#define GD 100    // z_dim of output (gen_Z rows)
#define NGB 625   // gene blocks of 16 (625*16 == 10000 exactly)
#define NGPAD 10016

__device__ __forceinline__ float gelu_exact(float x) {
    return 0.5f * x * (1.0f + erff(x * 0.70710678118654752f));
}
__device__ __forceinline__ ushort bf16bits(float x) {
    __hip_bfloat16 h = __float2bfloat16(x);
    return *reinterpret_cast<ushort*>(&h);
}
__device__ __forceinline__ f32x4 ntload4(const float* p) {
    return __builtin_nontemporal_load(reinterpret_cast<const f32x4*>(p));
}
__device__ __forceinline__ short8 ld8(const ushort* p) {
    return *reinterpret_cast<const short8*>(p);
}

// ---------------- Kernel 1: keys -> bf16 hi/lo A-fragments for S^T (slot perm cmap, validated R7)
__global__ void key_kernel(const float* __restrict__ rawZ,
                           const float* __restrict__ Wz1, const float* __restrict__ bz1,
                           const float* __restrict__ Wz2, const float* __restrict__ bz2,
                           ushort* __restrict__ khiA, ushort* __restrict__ kloA,
                           unsigned* __restrict__ kmax2u) {
    __shared__ float z[8][ZD];
    __shared__ float h[8][HD];
    const int t = threadIdx.x;
    const int c0 = blockIdx.x * 8;
    for (int idx = t; idx < 8 * ZD; idx += 256) {
        int cell = idx / ZD, i = idx - cell * ZD;
        z[cell][i] = rawZ[i * NCELL + c0 + cell];
    }
    __syncthreads();
    float a[8];
#pragma unroll
    for (int cl = 0; cl < 8; ++cl) a[cl] = bz1[t];
    for (int i = 0; i < ZD; ++i) {
        float wv = Wz1[i * HD + t];
#pragma unroll
        for (int cl = 0; cl < 8; ++cl) a[cl] += z[cl][i] * wv;
    }
#pragma unroll
    for (int cl = 0; cl < 8; ++cl) h[cl][t] = gelu_exact(a[cl]);
    __syncthreads();
    const int cell = t >> 5, kk = t & 31;
    float b = bz2[kk];
    for (int j = 0; j < HD; ++j) b += h[cell][j] * Wz2[j * KD + kk];
    const int c = c0 + cell;
    const int c16 = c & 15;
    const int G = c16 >> 2;
    const int s = (c16 & 3) | ((((G & 1) << 1) | (G >> 1)) << 2);  // slot = (c&3) | cmap(G)<<2
    __hip_bfloat16 hi = __float2bfloat16(b);
    float hif = __bfloat162float(hi);
    int idx = ((c >> 4) * 64 + s + 16 * (kk >> 3)) * 8 + (kk & 7);
    khiA[idx] = *reinterpret_cast<ushort*>(&hi);
    kloA[idx] = bf16bits(b - hif);
    float sq = b * b;
#pragma unroll
    for (int off = 16; off > 0; off >>= 1) sq += __shfl_xor(sq, off, 32);
    if (kk == 0) atomicMax(kmax2u, __float_as_uint(sq));
}

// ---------------- Kernel 2: q -> bf16 hi/lo B-fragments (padded to 10016 genes), Mg bound
__global__ void query_kernel(const float* __restrict__ Grep,
                             const float* __restrict__ Wg1, const float* __restrict__ bg1,
                             const float* __restrict__ Wg2, const float* __restrict__ bg2,
                             const unsigned* __restrict__ kmax2u,
                             ushort* __restrict__ qBhi, ushort* __restrict__ qBlo,
                             float* __restrict__ Mg) {
    __shared__ float gr[8][GD];
    __shared__ float hq[8][KD];
    const int t = threadIdx.x;
    const int g0 = blockIdx.x * 8;
    for (int idx = t; idx < 8 * GD; idx += 256) {
        int ge = idx / GD, i = idx - ge * GD;
        int g = g0 + ge;
        gr[ge][i] = (g < NGENE) ? Grep[(size_t)g * GD + i] : 0.0f;
    }
    __syncthreads();
    const int ge = t >> 5, kk = t & 31;
    float a = bg1[kk];
    for (int i = 0; i < GD; ++i) a += gr[ge][i] * Wg1[i * KD + kk];
    hq[ge][kk] = gelu_exact(a);
    __syncthreads();
    float b = bg2[kk];
#pragma unroll
    for (int j = 0; j < KD; ++j) b += hq[ge][j] * Wg2[j * KD + kk];
    float qv = b * 0.17677669529663687f; // fold 1/sqrt(d_k)
    const int g = g0 + ge;
    __hip_bfloat16 hi = __float2bfloat16(qv);
    float hif = __bfloat162float(hi);
    int idx = ((g >> 4) * 64 + (g & 15) + 16 * (kk >> 3)) * 8 + (kk & 7);
    qBhi[idx] = *reinterpret_cast<ushort*>(&hi);
    qBlo[idx] = bf16bits(qv - hif);
    float sq = qv * qv;
#pragma unroll
    for (int off = 16; off > 0; off >>= 1) sq += __shfl_xor(sq, off, 32);
    if (kk == 0) {
        float km2 = __uint_as_float(*kmax2u);
        Mg[g] = sqrtf(sq * km2) + 25.0f;   // static softmax shift; exp(l-M) <= 1 always
    }
}

// ---------------- Kernel 3: genZB — gen_Z bf16, PV B-frag order, k-cell order = tau (validated R7)
__global__ void vprep_kernel(const float* __restrict__ genZ, ushort* __restrict__ genZB) {
    int o = blockIdx.x * 256 + threadIdx.x; // 1,048,576 total
    int j = o & 7;
    int tj = (j & 1) | ((j & 2) << 1) | ((j & 4) >> 1);
    int l = (o >> 3) & 63;
    int db = (o >> 9) & 7;
    int cb = o >> 12;
    int c = cb * 32 + ((l >> 4) & 3) * 8 + tj;
    int d = db * 16 + (l & 15);
    float v = (d < GD) ? genZ[d * NCELL + c] : 0.0f;
    genZB[o] = bf16bits(v);
}

// ---------------- Kernel 4: fused partial — zero LDS/barriers + REGISTER double-buffered
// software pipeline (prefetch distance 1, named A/B sets, peeled epilogue). The whole point:
// keep all 13 loads of the NEXT step in flight while computing the current step.
#define STEP_COMPUTE(kh0_, kh1_, kl0_, kl1_, u0_, u1_, v0_, v1_, v2_, v3_, v4_, v5_, v6_)   \
    do {                                                                                    \
        __builtin_amdgcn_s_setprio(1);                                                      \
        f32x4 s0 = __builtin_amdgcn_mfma_f32_16x16x32_bf16(kh0_, qh, z4, 0, 0, 0);          \
        s0 = __builtin_amdgcn_mfma_f32_16x16x32_bf16(kl0_, qh, s0, 0, 0, 0);                \
        s0 = __builtin_amdgcn_mfma_f32_16x16x32_bf16(kh0_, ql, s0, 0, 0, 0);                \
        f32x4 s1 = __builtin_amdgcn_mfma_f32_16x16x32_bf16(kh1_, qh, z4, 0, 0, 0);          \
        s1 = __builtin_amdgcn_mfma_f32_16x16x32_bf16(kl1_, qh, s1, 0, 0, 0);                \
        s1 = __builtin_amdgcn_mfma_f32_16x16x32_bf16(kh1_, ql, s1, 0, 0, 0);                \
        float p0 = __expf(s0.x + u0_.x + negM);                                             \
        float p1 = __expf(s0.y + u0_.y + negM);                                             \
        float p2 = __expf(s0.z + u0_.z + negM);                                             \
        float p3 = __expf(s0.w + u0_.w + negM);                                             \
        float p4 = __expf(s1.x + u1_.x + negM);                                             \
        float p5 = __expf(s1.y + u1_.y + negM);                                             \
        float p6 = __expf(s1.z + u1_.z + negM);                                             \
        float p7 = __expf(s1.w + u1_.w + negM);                                             \
        L += ((p0 + p1) + (p2 + p3)) + ((p4 + p5) + (p6 + p7));                             \
        unsigned w00, w01, w10, w11;                                                        \
        asm("v_cvt_pk_bf16_f32 %0, %1, %2" : "=v"(w00) : "v"(p0), "v"(p1));                 \
        asm("v_cvt_pk_bf16_f32 %0, %1, %2" : "=v"(w01) : "v"(p2), "v"(p3));                 \
        asm("v_cvt_pk_bf16_f32 %0, %1, %2" : "=v"(w10) : "v"(p4), "v"(p5));                 \
        asm("v_cvt_pk_bf16_f32 %0, %1, %2" : "=v"(w11) : "v"(p6), "v"(p7));                 \
        uint2v rA = __builtin_amdgcn_permlane32_swap(w00, w10, false, false);               \
        uint2v rB = __builtin_amdgcn_permlane32_swap(w01, w11, false, false);               \
        uint4v pau = {rA.x, rA.y, rB.x, rB.y};                                              \
        short8 pa = *reinterpret_cast<short8*>(&pau);                                       \
        acc[0] = __builtin_amdgcn_mfma_f32_16x16x32_bf16(pa, v0_, acc[0], 0, 0, 0);         \
        acc[1] = __builtin_amdgcn_mfma_f32_16x16x32_bf16(pa, v1_, acc[1], 0, 0, 0);         \
        acc[2] = __builtin_amdgcn_mfma_f32_16x16x32_bf16(pa, v2_, acc[2], 0, 0, 0);         \
        acc[3] = __builtin_amdgcn_mfma_f32_16x16x32_bf16(pa, v3_, acc[3], 0, 0, 0);         \
        acc[4] = __builtin_amdgcn_mfma_f32_16x16x32_bf16(pa, v4_, acc[4], 0, 0, 0);         \
        acc[5] = __builtin_amdgcn_mfma_f32_16x16x32_bf16(pa, v5_, acc[5], 0, 0, 0);         \
        acc[6] = __builtin_amdgcn_mfma_f32_16x16x32_bf16(pa, v6_, acc[6], 0, 0, 0);         \
        __builtin_amdgcn_s_setprio(0);                                                      \
    } while (0)

__launch_bounds__(256)
__global__ void fused_kernel(const float* __restrict__ gumbel,
                             const ushort* __restrict__ khiA, const ushort* __restrict__ kloA,
                             const ushort* __restrict__ qBhi, const ushort* __restrict__ qBlo,
                             const float* __restrict__ Mg,
                             const ushort* __restrict__ genZB,
                             float* __restrict__ part, float* __restrict__ Lpart,
                             int Q, int cells_pw) {
    const int t = threadIdx.x, lane = t & 63, w = t >> 6;
    const int b = blockIdx.x;
    const int q = b % Q;            // Q==8: q == XCD id under round-robin dispatch
    const int ib = b / Q;
    const int gblk = ib * 4 + w;
    if (gblk >= NGB) return;
    const int g0 = gblk * 16;
    const int cbase = q * cells_pw;
    const int nsteps = cells_pw >> 5;   // 32 at Q=8; always even
    const int wv = q * NGB + gblk;

    const int gx = lane & 15, bq = lane >> 4;
    const int cmap4 = (((bq & 1) << 1) | (bq >> 1)) << 2;   // cmap(b)*4 in {0,8,4,12}
    const float negM = -Mg[g0 + gx];
    short8 qh = ld8(qBhi + (size_t)gblk * 512 + lane * 8);
    short8 ql = ld8(qBlo + (size_t)gblk * 512 + lane * 8);

    const float* gp   = gumbel + (size_t)(g0 + gx) * NCELL + cbase + cmap4;
    const ushort* kp  = khiA + (size_t)(cbase >> 4) * 512 + lane * 8;
    const ushort* klp = kloA + (size_t)(cbase >> 4) * 512 + lane * 8;
    const short8* vb  = reinterpret_cast<const short8*>(genZB) + (size_t)(cbase >> 5) * 512 + lane;

    f32x4 acc[7];
#pragma unroll
    for (int i = 0; i < 7; ++i) acc[i] = f32x4{0.f, 0.f, 0.f, 0.f};
    float L = 0.f;
    const f32x4 z4 = {0.f, 0.f, 0.f, 0.f};

    // ---- prologue: A <- step 0; advance pointers to step 1
    short8 khA0 = ld8(kp),        khA1 = ld8(kp + 512);
    short8 klA0 = ld8(klp),       klA1 = ld8(klp + 512);
    f32x4  uA0  = ntload4(gp),    uA1  = ntload4(gp + 16);
    short8 vA0 = vb[0],  vA1 = vb[64],  vA2 = vb[128], vA3 = vb[192];
    short8 vA4 = vb[256], vA5 = vb[320], vA6 = vb[384];
    kp += 1024; klp += 1024; gp += 32; vb += 512;

    for (int it = 0; it < nsteps / 2 - 1; ++it) {
        // B <- step 2it+1
        short8 khB0 = ld8(kp),      khB1 = ld8(kp + 512);
        short8 klB0 = ld8(klp),     klB1 = ld8(klp + 512);
        f32x4  uB0  = ntload4(gp),  uB1  = ntload4(gp + 16);
        short8 vB0 = vb[0],  vB1 = vb[64],  vB2 = vb[128], vB3 = vb[192];
        short8 vB4 = vb[256], vB5 = vb[320], vB6 = vb[384];
        // compute step 2it (A)
        STEP_COMPUTE(khA0, khA1, klA0, klA1, uA0, uA1, vA0, vA1, vA2, vA3, vA4, vA5, vA6);
        // A <- step 2it+2
        khA0 = ld8(kp + 1024);      khA1 = ld8(kp + 1536);
        klA0 = ld8(klp + 1024);     klA1 = ld8(klp + 1536);
        uA0  = ntload4(gp + 32);    uA1  = ntload4(gp + 48);
        vA0 = vb[512]; vA1 = vb[576]; vA2 = vb[640]; vA3 = vb[704];
        vA4 = vb[768]; vA5 = vb[832]; vA6 = vb[896];
        kp += 2048; klp += 2048; gp += 64; vb += 1024;
        // compute step 2it+1 (B)
        STEP_COMPUTE(khB0, khB1, klB0, klB1, uB0, uB1, vB0, vB1, vB2, vB3, vB4, vB5, vB6);
    }
    // ---- peeled last pair: B <- step nsteps-1; compute A(nsteps-2); compute B
    {
        short8 khB0 = ld8(kp),      khB1 = ld8(kp + 512);
        short8 klB0 = ld8(klp),     klB1 = ld8(klp + 512);
        f32x4  uB0  = ntload4(gp),  uB1  = ntload4(gp + 16);
        short8 vB0 = vb[0],  vB1 = vb[64],  vB2 = vb[128], vB3 = vb[192];
        short8 vB4 = vb[256], vB5 = vb[320], vB6 = vb[384];
        STEP_COMPUTE(khA0, khA1, klA0, klA1, uA0, uA1, vA0, vA1, vA2, vA3, vA4, vA5, vA6);
        STEP_COMPUTE(khB0, khB1, klB0, klB1, uB0, uB1, vB0, vB1, vB2, vB3, vB4, vB5, vB6);
    }

    // L: lanes sharing gx hold disjoint-cell partials of the same gene
    L += __shfl_xor(L, 16, 64);
    L += __shfl_xor(L, 32, 64);
    if (lane < 16)
        __builtin_nontemporal_store(L, Lpart + (size_t)wv * 16 + lane);
    float* pp = part + (size_t)wv * 7 * 256;
#pragma unroll
    for (int tile = 0; tile < 7; ++tile)
        __builtin_nontemporal_store(acc[tile],
            reinterpret_cast<f32x4*>(pp + tile * 256 + lane * 4));
}

// ---------------- Kernel 5: combine partials + normalize
__global__ void combine_kernel(const float* __restrict__ part, const float* __restrict__ Lpart,
                               int Q, float* __restrict__ out) {
    const int gb = blockIdx.x;   // 625
    const int t = threadIdx.x;   // 512
    __shared__ float Linv[16];
    if (t < 16) {
        float s = 0.f;
        for (int qq = 0; qq < Q; ++qq) s += Lpart[(size_t)(qq * NGB + gb) * 16 + t];
        Linv[t] = 1.0f / s;
    }
    __syncthreads();
    if (t < 448) {
        const int tile = t >> 6, lane = t & 63;
        const int d = tile * 16 + (lane & 15);
        f32x4 ssum = {0.f, 0.f, 0.f, 0.f};
        for (int qq = 0; qq < Q; ++qq)
            ssum += *reinterpret_cast<const f32x4*>(
                part + ((size_t)(qq * NGB + gb) * 7 + tile) * 256 + lane * 4);
        if (d < GD) {
            const int gl0 = 4 * (lane >> 4);   // C/D: col=lane&15 (d), row=4*(lane>>4)+r (gene)
            f32x4 li = {Linv[gl0], Linv[gl0 + 1], Linv[gl0 + 2], Linv[gl0 + 3]};
            f32x4 o = ssum * li;
            *reinterpret_cast<f32x4*>(out + (size_t)d * NGENE + gb * 16 + gl0) = o;
        }
    }
}

extern "C" void kernel_launch(void* const* d_in, const int* in_sizes, int n_in,
                              void* d_out, int out_size, void* d_ws, size_t ws_size,
                              hipStream_t stream) {
    const float* rawZ  = (const float*)d_in[0];
    const float* genZ  = (const float*)d_in[1];
    const float* Grep  = (const float*)d_in[2];
    const float* gumb  = (const float*)d_in[3];
    const float* Wz1   = (const float*)d_in[4];
    const float* bz1   = (const float*)d_in[5];
    const float* Wz2   = (const float*)d_in[6];
    const float* bz2   = (const float*)d_in[7];
    const float* Wg1   = (const float*)d_in[8];
    const float* bg1   = (const float*)d_in[9];
    const float* Wg2   = (const float*)d_in[10];
    const float* bg2   = (const float*)d_in[11];
    float* out = (float*)d_out;

    char* ws = (char*)d_ws;
    ushort*   khiA  = (ushort*)ws;                           // 512K
    ushort*   kloA  = (ushort*)(ws + 524288);                // 512K
    ushort*   qBhi  = (ushort*)(ws + 1048576);               // 640K (10016 genes)
    ushort*   qBlo  = (ushort*)(ws + 1703936);               // 640K
    ushort*   genZB = (ushort*)(ws + 2359296);               // 2M
    float*    MgA   = (float*)(ws + 4456448);                // 40K
    unsigned* kmax  = (unsigned*)(ws + 4497408);             // 256B
    const size_t base_off = 4497664;

    // cell-split factor: waves = 625*Q; fall back if workspace too small
    const size_t per_q = (size_t)NGB * (7 * 256 + 16) * 4;   // part + Lpart per q-slice
    int Q = 8;
    while (Q > 1 && base_off + (size_t)Q * per_q > ws_size) Q >>= 1;
    float* partA  = (float*)(ws + base_off);
    float* LpartA = partA + (size_t)Q * NGB * 7 * 256;

    hipMemsetAsync(kmax, 0, 4, stream);
    hipLaunchKernelGGL(key_kernel,   dim3(NCELL / 8), dim3(256), 0, stream,
                       rawZ, Wz1, bz1, Wz2, bz2, khiA, kloA, kmax);
    hipLaunchKernelGGL(query_kernel, dim3(NGPAD / 8), dim3(256), 0, stream,
                       Grep, Wg1, bg1, Wg2, bg2, kmax, qBhi, qBlo, MgA);
    hipLaunchKernelGGL(vprep_kernel, dim3((256 * 8 * 64 * 8) / 256), dim3(256), 0, stream,
                       genZ, genZB);
    hipLaunchKernelGGL(fused_kernel, dim3(Q * 157), dim3(256), 0, stream,
                       gumb, khiA, kloA, qBhi, qBlo, MgA, genZB, partA, LpartA,
                       Q, NCELL / Q);
    hipLaunchKernelGGL(combine_kernel, dim3(NGB), dim3(512), 0, stream,
                       partA, LpartA, Q, out);
}

// Round 9
// 209.639 us; speedup vs baseline: 1.3628x; 1.1773x over previous
//
#include <hip/hip_runtime.h>
#include <hip/hip_bf16.h>

typedef __attribute__((ext_vector_type(8))) short short8;
typedef __attribute__((ext_vector_type(4))) float f32x4;
typedef __attribute__((ext_vector_type(4))) unsigned uint4v;
typedef __attribute__((ext_vector_type(2))) unsigned uint2v;

#define NCELL 8192
#define NGENE 10000
#define KD 32
#define ZD 100
#define HD 256
#define GD 100    // z_dim of output (gen_Z rows)
#define NGB 625   // gene units of 16 (625*16 == 10000 exactly)
#define NGPAD 10016
#define QSL 16    // cell slices of 512

__device__ __forceinline__ float gelu_exact(float x) {
    return 0.5f * x * (1.0f + erff(x * 0.70710678118654752f));
}
__device__ __forceinline__ ushort bf16bits(float x) {
    __hip_bfloat16 h = __float2bfloat16(x);
    return *reinterpret_cast<ushort*>(&h);
}
__device__ __forceinline__ f32x4 ntload4(const float* p) {
    return __builtin_nontemporal_load(reinterpret_cast<const f32x4*>(p));
}
__device__ __forceinline__ short8 ld8(const ushort* p) {
    return *reinterpret_cast<const short8*>(p);
}

// ---------------- Kernel 1: keys -> bf16 hi/lo A-fragments for S^T (slot perm cmap, validated R7)
__global__ void key_kernel(const float* __restrict__ rawZ,
                           const float* __restrict__ Wz1, const float* __restrict__ bz1,
                           const float* __restrict__ Wz2, const float* __restrict__ bz2,
                           ushort* __restrict__ khiA, ushort* __restrict__ kloA,
                           unsigned* __restrict__ kmax2u) {
    __shared__ float z[8][ZD];
    __shared__ float h[8][HD];
    const int t = threadIdx.x;
    const int c0 = blockIdx.x * 8;
    for (int idx = t; idx < 8 * ZD; idx += 256) {
        int cell = idx / ZD, i = idx - cell * ZD;
        z[cell][i] = rawZ[i * NCELL + c0 + cell];
    }
    __syncthreads();
    float a[8];
#pragma unroll
    for (int cl = 0; cl < 8; ++cl) a[cl] = bz1[t];
    for (int i = 0; i < ZD; ++i) {
        float wv = Wz1[i * HD + t];
#pragma unroll
        for (int cl = 0; cl < 8; ++cl) a[cl] += z[cl][i] * wv;
    }
#pragma unroll
    for (int cl = 0; cl < 8; ++cl) h[cl][t] = gelu_exact(a[cl]);
    __syncthreads();
    const int cell = t >> 5, kk = t & 31;
    float b = bz2[kk];
    for (int j = 0; j < HD; ++j) b += h[cell][j] * Wz2[j * KD + kk];
    const int c = c0 + cell;
    const int c16 = c & 15;
    const int G = c16 >> 2;
    const int s = (c16 & 3) | ((((G & 1) << 1) | (G >> 1)) << 2);  // slot = (c&3) | cmap(G)<<2
    __hip_bfloat16 hi = __float2bfloat16(b);
    float hif = __bfloat162float(hi);
    int idx = ((c >> 4) * 64 + s + 16 * (kk >> 3)) * 8 + (kk & 7);
    khiA[idx] = *reinterpret_cast<ushort*>(&hi);
    kloA[idx] = bf16bits(b - hif);
    float sq = b * b;
#pragma unroll
    for (int off = 16; off > 0; off >>= 1) sq += __shfl_xor(sq, off, 32);
    if (kk == 0) atomicMax(kmax2u, __float_as_uint(sq));
}

// ---------------- Kernel 2: q -> bf16 hi/lo B-fragments (padded to 10016 genes), Mg bound
__global__ void query_kernel(const float* __restrict__ Grep,
                             const float* __restrict__ Wg1, const float* __restrict__ bg1,
                             const float* __restrict__ Wg2, const float* __restrict__ bg2,
                             const unsigned* __restrict__ kmax2u,
                             ushort* __restrict__ qBhi, ushort* __restrict__ qBlo,
                             float* __restrict__ Mg) {
    __shared__ float gr[8][GD];
    __shared__ float hq[8][KD];
    const int t = threadIdx.x;
    const int g0 = blockIdx.x * 8;
    for (int idx = t; idx < 8 * GD; idx += 256) {
        int ge = idx / GD, i = idx - ge * GD;
        int g = g0 + ge;
        gr[ge][i] = (g < NGENE) ? Grep[(size_t)g * GD + i] : 0.0f;
    }
    __syncthreads();
    const int ge = t >> 5, kk = t & 31;
    float a = bg1[kk];
    for (int i = 0; i < GD; ++i) a += gr[ge][i] * Wg1[i * KD + kk];
    hq[ge][kk] = gelu_exact(a);
    __syncthreads();
    float b = bg2[kk];
#pragma unroll
    for (int j = 0; j < KD; ++j) b += hq[ge][j] * Wg2[j * KD + kk];
    float qv = b * 0.17677669529663687f; // fold 1/sqrt(d_k)
    const int g = g0 + ge;
    __hip_bfloat16 hi = __float2bfloat16(qv);
    float hif = __bfloat162float(hi);
    int idx = ((g >> 4) * 64 + (g & 15) + 16 * (kk >> 3)) * 8 + (kk & 7);
    qBhi[idx] = *reinterpret_cast<ushort*>(&hi);
    qBlo[idx] = bf16bits(qv - hif);
    float sq = qv * qv;
#pragma unroll
    for (int off = 16; off > 0; off >>= 1) sq += __shfl_xor(sq, off, 32);
    if (kk == 0) {
        float km2 = __uint_as_float(*kmax2u);
        Mg[g] = sqrtf(sq * km2) + 25.0f;   // static softmax shift; exp(l-M) <= 1 always
    }
}

// ---------------- Kernel 3: genZB — gen_Z bf16, PV B-frag, tau k-order, DB-MAJOR layout:
// idx = ((db*256 + cb)*64 + l)*8 + j, db in [0,7) — 512-cell slices are 7 contiguous 16KB pieces
__global__ void vprep_kernel(const float* __restrict__ genZ, ushort* __restrict__ genZB) {
    int o = blockIdx.x * 256 + threadIdx.x; // 917,504 total
    int j = o & 7;
    int tj = (j & 1) | ((j & 2) << 1) | ((j & 4) >> 1);   // tau
    int l = (o >> 3) & 63;
    int cb = (o >> 9) & 255;
    int db = o >> 17;
    int c = cb * 32 + ((l >> 4) & 3) * 8 + tj;
    int d = db * 16 + (l & 15);
    float v = (d < GD) ? genZ[(size_t)d * NCELL + c] : 0.0f;
    genZB[o] = bf16bits(v);
}

// ---------------- Kernel 4: fused partial — V staged ONCE in 112KB LDS per block, then
// barrier-free gene-unit loop. Block = slice q (512 cells) x 8 waves; wave loops ~5 units
// of 16 genes. Per step: 4 K-loads(L2) + 2 gumbel(NT) + 7 V ds_reads -> 13 MFMA -> 8 exp.
// K+gumbel register double-buffered (R8 pipeline).
#define STEP_COMPUTE(kh0_, kh1_, kl0_, kl1_, u0_, u1_)                                      \
    do {                                                                                    \
        short8 v0 = ld8(vp);         short8 v1 = ld8(vp + 8192);                            \
        short8 v2 = ld8(vp + 16384); short8 v3 = ld8(vp + 24576);                           \
        short8 v4 = ld8(vp + 32768); short8 v5 = ld8(vp + 40960);                           \
        short8 v6 = ld8(vp + 49152); vp += 512;                                             \
        __builtin_amdgcn_s_setprio(1);                                                      \
        f32x4 s0 = __builtin_amdgcn_mfma_f32_16x16x32_bf16(kh0_, qh, z4, 0, 0, 0);          \
        s0 = __builtin_amdgcn_mfma_f32_16x16x32_bf16(kl0_, qh, s0, 0, 0, 0);                \
        s0 = __builtin_amdgcn_mfma_f32_16x16x32_bf16(kh0_, ql, s0, 0, 0, 0);                \
        f32x4 s1 = __builtin_amdgcn_mfma_f32_16x16x32_bf16(kh1_, qh, z4, 0, 0, 0);          \
        s1 = __builtin_amdgcn_mfma_f32_16x16x32_bf16(kl1_, qh, s1, 0, 0, 0);                \
        s1 = __builtin_amdgcn_mfma_f32_16x16x32_bf16(kh1_, ql, s1, 0, 0, 0);                \
        float p0 = __expf(s0.x + u0_.x + negM);                                             \
        float p1 = __expf(s0.y + u0_.y + negM);                                             \
        float p2 = __expf(s0.z + u0_.z + negM);                                             \
        float p3 = __expf(s0.w + u0_.w + negM);                                             \
        float p4 = __expf(s1.x + u1_.x + negM);                                             \
        float p5 = __expf(s1.y + u1_.y + negM);                                             \
        float p6 = __expf(s1.z + u1_.z + negM);                                             \
        float p7 = __expf(s1.w + u1_.w + negM);                                             \
        L += ((p0 + p1) + (p2 + p3)) + ((p4 + p5) + (p6 + p7));                             \
        unsigned w00, w01, w10, w11;                                                        \
        asm("v_cvt_pk_bf16_f32 %0, %1, %2" : "=v"(w00) : "v"(p0), "v"(p1));                 \
        asm("v_cvt_pk_bf16_f32 %0, %1, %2" : "=v"(w01) : "v"(p2), "v"(p3));                 \
        asm("v_cvt_pk_bf16_f32 %0, %1, %2" : "=v"(w10) : "v"(p4), "v"(p5));                 \
        asm("v_cvt_pk_bf16_f32 %0, %1, %2" : "=v"(w11) : "v"(p6), "v"(p7));                 \
        uint2v rA = __builtin_amdgcn_permlane32_swap(w00, w10, false, false);               \
        uint2v rB = __builtin_amdgcn_permlane32_swap(w01, w11, false, false);               \
        uint4v pau = {rA.x, rA.y, rB.x, rB.y};                                              \
        short8 pa = *reinterpret_cast<short8*>(&pau);                                       \
        acc[0] = __builtin_amdgcn_mfma_f32_16x16x32_bf16(pa, v0, acc[0], 0, 0, 0);          \
        acc[1] = __builtin_amdgcn_mfma_f32_16x16x32_bf16(pa, v1, acc[1], 0, 0, 0);          \
        acc[2] = __builtin_amdgcn_mfma_f32_16x16x32_bf16(pa, v2, acc[2], 0, 0, 0);          \
        acc[3] = __builtin_amdgcn_mfma_f32_16x16x32_bf16(pa, v3, acc[3], 0, 0, 0);          \
        acc[4] = __builtin_amdgcn_mfma_f32_16x16x32_bf16(pa, v4, acc[4], 0, 0, 0);          \
        acc[5] = __builtin_amdgcn_mfma_f32_16x16x32_bf16(pa, v5, acc[5], 0, 0, 0);          \
        acc[6] = __builtin_amdgcn_mfma_f32_16x16x32_bf16(pa, v6, acc[6], 0, 0, 0);          \
        __builtin_amdgcn_s_setprio(0);                                                      \
    } while (0)

__launch_bounds__(512)
__global__ void fused_kernel(const float* __restrict__ gumbel,
                             const ushort* __restrict__ khiA, const ushort* __restrict__ kloA,
                             const ushort* __restrict__ qBhi, const ushort* __restrict__ qBlo,
                             const float* __restrict__ Mg,
                             const ushort* __restrict__ genZB,
                             float* __restrict__ part, float* __restrict__ Lpart) {
    __shared__ __align__(16) ushort vlds[7 * 8192];   // 112 KB: V slice, db-major
    const int t = threadIdx.x, lane = t & 63, w = t >> 6;
    const int b = blockIdx.x;
    const int q = b & 15;          // slice; b%8 pattern -> 2 slices per XCD (K slice L2-hot)
    const int ib = b >> 4;         // 16 blocks per slice
    // ---- stage V slice (7 contiguous 16KB pieces, linear copy)
    {
        f32x4* vdst = reinterpret_cast<f32x4*>(vlds);
        const f32x4* vsrc = reinterpret_cast<const f32x4*>(genZB);
        for (int i = t; i < 7168; i += 512) {
            int db = i >> 10, rem = i & 1023;
            vdst[i] = vsrc[db * 16384 + q * 1024 + rem];
        }
    }
    __syncthreads();   // the only barrier

    const int gx = lane & 15, bq = lane >> 4;
    const int cmap4 = (((bq & 1) << 1) | (bq >> 1)) << 2;   // {0,8,4,12}
    const ushort* kbase  = khiA + q * 16384 + lane * 8;
    const ushort* klbase = kloA + q * 16384 + lane * 8;
    const f32x4 z4 = {0.f, 0.f, 0.f, 0.f};

    for (int u = ib * 8 + w; u < NGB; u += 128) {
        const float negM = -Mg[u * 16 + gx];
        short8 qh = ld8(qBhi + (size_t)u * 512 + lane * 8);
        short8 ql = ld8(qBlo + (size_t)u * 512 + lane * 8);
        const float* gp = gumbel + (size_t)(u * 16 + gx) * NCELL + q * 512 + cmap4;
        const ushort* kp  = kbase;
        const ushort* klp = klbase;
        const ushort* vp  = vlds + lane * 8;
        f32x4 acc[7];
#pragma unroll
        for (int i = 0; i < 7; ++i) acc[i] = z4;
        float L = 0.f;
        // prologue: A <- step 0
        short8 khA0 = ld8(kp),   khA1 = ld8(kp + 512);
        short8 klA0 = ld8(klp),  klA1 = ld8(klp + 512);
        f32x4  uA0  = ntload4(gp), uA1 = ntload4(gp + 16);
        kp += 1024; klp += 1024; gp += 32;
        for (int it = 0; it < 7; ++it) {
            short8 khB0 = ld8(kp),   khB1 = ld8(kp + 512);
            short8 klB0 = ld8(klp),  klB1 = ld8(klp + 512);
            f32x4  uB0  = ntload4(gp), uB1 = ntload4(gp + 16);
            STEP_COMPUTE(khA0, khA1, klA0, klA1, uA0, uA1);
            khA0 = ld8(kp + 1024);  khA1 = ld8(kp + 1536);
            klA0 = ld8(klp + 1024); klA1 = ld8(klp + 1536);
            uA0  = ntload4(gp + 32); uA1 = ntload4(gp + 48);
            kp += 2048; klp += 2048; gp += 64;
            STEP_COMPUTE(khB0, khB1, klB0, klB1, uB0, uB1);
        }
        {   // peeled steps 14,15
            short8 khB0 = ld8(kp),   khB1 = ld8(kp + 512);
            short8 klB0 = ld8(klp),  klB1 = ld8(klp + 512);
            f32x4  uB0  = ntload4(gp), uB1 = ntload4(gp + 16);
            STEP_COMPUTE(khA0, khA1, klA0, klA1, uA0, uA1);
            STEP_COMPUTE(khB0, khB1, klB0, klB1, uB0, uB1);
        }
        // L: lanes sharing gx hold disjoint-cell partials of the same gene
        L += __shfl_xor(L, 16, 64);
        L += __shfl_xor(L, 32, 64);
        const int wv = q * NGB + u;
        if (lane < 16)
            __builtin_nontemporal_store(L, Lpart + (size_t)wv * 16 + lane);
        float* pp = part + (size_t)wv * 7 * 256;
#pragma unroll
        for (int tile = 0; tile < 7; ++tile)
            __builtin_nontemporal_store(acc[tile],
                reinterpret_cast<f32x4*>(pp + tile * 256 + lane * 4));
    }
}

// ---------------- Kernel 5: combine 16 slice-partials + normalize
__global__ void combine_kernel(const float* __restrict__ part, const float* __restrict__ Lpart,
                               float* __restrict__ out) {
    const int gb = blockIdx.x;   // 625
    const int t = threadIdx.x;   // 512
    __shared__ float Linv[16];
    if (t < 16) {
        float s = 0.f;
        for (int qq = 0; qq < QSL; ++qq) s += Lpart[(size_t)(qq * NGB + gb) * 16 + t];
        Linv[t] = 1.0f / s;
    }
    __syncthreads();
    if (t < 448) {
        const int tile = t >> 6, lane = t & 63;
        const int d = tile * 16 + (lane & 15);
        f32x4 ssum = {0.f, 0.f, 0.f, 0.f};
        for (int qq = 0; qq < QSL; ++qq)
            ssum += *reinterpret_cast<const f32x4*>(
                part + ((size_t)(qq * NGB + gb) * 7 + tile) * 256 + lane * 4);
        if (d < GD) {
            const int gl0 = 4 * (lane >> 4);   // C/D: col=lane&15 (d), row=4*(lane>>4)+r (gene)
            f32x4 li = {Linv[gl0], Linv[gl0 + 1], Linv[gl0 + 2], Linv[gl0 + 3]};
            f32x4 o = ssum * li;
            *reinterpret_cast<f32x4*>(out + (size_t)d * NGENE + gb * 16 + gl0) = o;
        }
    }
}

extern "C" void kernel_launch(void* const* d_in, const int* in_sizes, int n_in,
                              void* d_out, int out_size, void* d_ws, size_t ws_size,
                              hipStream_t stream) {
    const float* rawZ  = (const float*)d_in[0];
    const float* genZ  = (const float*)d_in[1];
    const float* Grep  = (const float*)d_in[2];
    const float* gumb  = (const float*)d_in[3];
    const float* Wz1   = (const float*)d_in[4];
    const float* bz1   = (const float*)d_in[5];
    const float* Wz2   = (const float*)d_in[6];
    const float* bz2   = (const float*)d_in[7];
    const float* Wg1   = (const float*)d_in[8];
    const float* bg1   = (const float*)d_in[9];
    const float* Wg2   = (const float*)d_in[10];
    const float* bg2   = (const float*)d_in[11];
    float* out = (float*)d_out;

    char* ws = (char*)d_ws;
    ushort*   khiA  = (ushort*)ws;                           // 512K
    ushort*   kloA  = (ushort*)(ws + 524288);                // 512K
    ushort*   qBhi  = (ushort*)(ws + 1048576);               // 640K (10016 genes)
    ushort*   qBlo  = (ushort*)(ws + 1703936);               // 640K
    ushort*   genZB = (ushort*)(ws + 2359296);               // 1.75M (7 db, db-major)
    float*    MgA   = (float*)(ws + 4456448);                // 40K
    unsigned* kmax  = (unsigned*)(ws + 4497408);             // 256B
    const size_t base_off = 4497664;

    float* partA  = (float*)(ws + base_off);                 // 16*625*7*256*4 = 71.7 MB
    float* LpartA = partA + (size_t)QSL * NGB * 7 * 256;     // 640 KB (ws measured ~1.31 GB)

    hipMemsetAsync(kmax, 0, 4, stream);
    hipLaunchKernelGGL(key_kernel,   dim3(NCELL / 8), dim3(256), 0, stream,
                       rawZ, Wz1, bz1, Wz2, bz2, khiA, kloA, kmax);
    hipLaunchKernelGGL(query_kernel, dim3(NGPAD / 8), dim3(256), 0, stream,
                       Grep, Wg1, bg1, Wg2, bg2, kmax, qBhi, qBlo, MgA);
    hipLaunchKernelGGL(vprep_kernel, dim3(917504 / 256), dim3(256), 0, stream,
                       genZ, genZB);
    hipLaunchKernelGGL(fused_kernel, dim3(256), dim3(512), 0, stream,
                       gumb, khiA, kloA, qBhi, qBlo, MgA, genZB, partA, LpartA);
    hipLaunchKernelGGL(combine_kernel, dim3(NGB), dim3(512), 0, stream,
                       partA, LpartA, out);
}